// Round 14
// baseline (180.108 us; speedup 1.0000x reference)
//
#include <hip/hip_runtime.h>

// B=2, T=2048, C=1024, H=16, DQK=DV=64. Inputs fp32, output fp32, bf16 MFMA inside.

typedef short bf16x4 __attribute__((ext_vector_type(4)));
typedef short bf16x8 __attribute__((ext_vector_type(8)));
typedef float f32x4 __attribute__((ext_vector_type(4)));

#define MFMA_BF16 __builtin_amdgcn_mfma_f32_16x16x32_bf16

// log2(e)/8: Q pre-scale so softmax runs in base-2 domain (exp2 = bare v_exp_f32)
#define QSCALE 0.18033688011112042f

__device__ __forceinline__ unsigned short f2bf(float f) {
    union { float f; unsigned u; } un; un.f = f;
    unsigned r = un.u + 0x7fffu + ((un.u >> 16) & 1u);  // RNE
    return (unsigned short)(r >> 16);
}
__device__ __forceinline__ unsigned pk2(float a, float b) {
    return (unsigned)f2bf(a) | ((unsigned)f2bf(b) << 16);
}
// truncating pack of two floats into packed bf16x2
__device__ __forceinline__ unsigned pk2t(float a, float b) {
    union { float f; unsigned u; } ua, ub; ua.f = a; ub.f = b;
    return (ua.u >> 16) | (ub.u & 0xffff0000u);
}
__device__ __forceinline__ void gload16(const void* g, void* l) {
    __builtin_amdgcn_global_load_lds(
        (const __attribute__((address_space(1))) unsigned int*)g,
        (__attribute__((address_space(3))) unsigned int*)l, 16, 0, 0);
}

// ---------- fused prep: x/wq/wk/wv fp32->bf16, wo fp32->bf16 transposed ----------
__global__ __launch_bounds__(256) void prep(
    const float* __restrict__ x, const float* __restrict__ wq,
    const float* __restrict__ wk, const float* __restrict__ wv,
    const float* __restrict__ wo,
    unsigned short* __restrict__ x16, unsigned short* __restrict__ wq16,
    unsigned short* __restrict__ wk16, unsigned short* __restrict__ wv16,
    unsigned short* __restrict__ wot)
{
    const int bid = blockIdx.x;
    if (bid < 3584) {
        const float* s; unsigned short* d; int off;
        if (bid < 2048)      { s = x;  d = x16;  off = bid * 2048; }
        else if (bid < 2560) { s = wq; d = wq16; off = (bid - 2048) * 2048; }
        else if (bid < 3072) { s = wk; d = wk16; off = (bid - 2560) * 2048; }
        else                 { s = wv; d = wv16; off = (bid - 3072) * 2048; }
        int i = off + threadIdx.x * 8;
        float4 f0 = *(const float4*)&s[i], f1 = *(const float4*)&s[i + 4];
        uint4 o;
        o.x = pk2(f0.x, f0.y); o.y = pk2(f0.z, f0.w);
        o.z = pk2(f1.x, f1.y); o.w = pk2(f1.z, f1.w);
        *(uint4*)&d[i] = o;
    } else {
        // wo [K=1024][N=1024] -> wot [N][K] bf16
        __shared__ unsigned short t[64 * 72];
        const int b2 = bid - 3584;
        const int k0 = (b2 & 15) << 6, n0 = (b2 >> 4) << 6;
        const int r = threadIdx.x >> 2, cg = (threadIdx.x & 3) << 4;
        const float* src = &wo[(k0 + r) * 1024 + n0 + cg];
        #pragma unroll
        for (int j = 0; j < 16; j += 4) {
            float4 f = *(const float4*)&src[j];
            t[(cg + j + 0) * 72 + r] = f2bf(f.x);
            t[(cg + j + 1) * 72 + r] = f2bf(f.y);
            t[(cg + j + 2) * 72 + r] = f2bf(f.z);
            t[(cg + j + 3) * 72 + r] = f2bf(f.w);
        }
        __syncthreads();
        unsigned short* dst = &wot[(n0 + r) * 1024 + k0 + cg];
        unsigned short* tr = &t[r * 72 + cg];
        unsigned v[16];
        #pragma unroll
        for (int j = 0; j < 16; ++j) v[j] = tr[j];
        uint4 o0, o1;
        o0.x = v[0] | (v[1] << 16);   o0.y = v[2] | (v[3] << 16);
        o0.z = v[4] | (v[5] << 16);   o0.w = v[6] | (v[7] << 16);
        o1.x = v[8] | (v[9] << 16);   o1.y = v[10] | (v[11] << 16);
        o1.z = v[12] | (v[13] << 16); o1.w = v[14] | (v[15] << 16);
        *(uint4*)&dst[0] = o0;
        *(uint4*)&dst[8] = o1;
    }
}

// ---------- 128x64 bf16 GEMM, K=1024: BK=32 dbuf gload16, fully unrolled ----------
// R13 analysis: 128x128 at 3 blocks/CU (Occ 24%) can't hide the per-slab
// vmcnt(0)-before-barrier drain. 128x64 -> 24 KB LDS, 32-VGPR acc, 6 blocks/CU:
// double the co-resident blocks masking each drain. Staging: 3 gload16/thread/slab
// (rounds: sa rows 0-63, sa rows 64-127, sb rows 0-63).
__device__ __forceinline__ void gemm_body64(
    const unsigned short* __restrict__ A, const unsigned short* __restrict__ Bm,
    void* __restrict__ C, int m0, int n0, int mode, int ldc, float sc)
{
    __shared__ unsigned short sa[2][128 * 32];
    __shared__ unsigned short sb[2][64 * 32];
    const int tid = threadIdx.x, wave = tid >> 6, lane = tid & 63;
    const int l15 = lane & 15, l4 = lane >> 4;
    const int wm = (wave >> 1) << 6, wn = (wave & 1) << 5;

    const int r16 = lane >> 2;             // 0..15
    const int gcol = (lane & 3) << 3;      // 0,8,16,24
    const unsigned short* Ag0 = &A[(size_t)(m0 + wave * 16 + r16) * 1024 + gcol];
    const unsigned short* Ag1 = Ag0 + (size_t)64 * 1024;
    const unsigned short* Bg  = &Bm[(size_t)(n0 + wave * 16 + r16) * 1024 + gcol];
    const int lb0 = (wave * 16) * 32;      // wave-uniform LDS bases (elements)
    const int lb1 = (64 + wave * 16) * 32;

    gload16(Ag0, &sa[0][lb0]);
    gload16(Ag1, &sa[0][lb1]);
    gload16(Bg,  &sb[0][lb0]);
    __syncthreads();

    f32x4 acc[4][2] = {};

    #pragma unroll
    for (int kk = 0; kk < 32; ++kk) {
        const int cur = kk & 1;
        if (kk < 31) {
            const int off = (kk + 1) * 32;
            const int nxt = 1 - cur;
            gload16(Ag0 + off, &sa[nxt][lb0]);
            gload16(Ag1 + off, &sa[nxt][lb1]);
            gload16(Bg + off,  &sb[nxt][lb0]);
        }
        bf16x8 af[4], bf2[2];
        #pragma unroll
        for (int i = 0; i < 4; ++i)
            af[i] = *(const bf16x8*)&sa[cur][(wm + i * 16 + l15) * 32 + l4 * 8];
        #pragma unroll
        for (int j = 0; j < 2; ++j)
            bf2[j] = *(const bf16x8*)&sb[cur][(wn + j * 16 + l15) * 32 + l4 * 8];
        #pragma unroll
        for (int i = 0; i < 4; ++i)
            #pragma unroll
            for (int j = 0; j < 2; ++j)
                acc[i][j] = MFMA_BF16(af[i], bf2[j], acc[i][j], 0, 0, 0);
        __syncthreads();   // next-slab loads have flown during the MFMAs above
    }

    #pragma unroll
    for (int i = 0; i < 4; ++i)
        #pragma unroll
        for (int j = 0; j < 2; ++j)
            #pragma unroll
            for (int r = 0; r < 4; ++r) {
                int row = m0 + wm + i * 16 + l4 * 4 + r;
                int col = n0 + wn + j * 16 + l15;
                float val = acc[i][j][r];
                if (mode == 0) {
                    int nb = row >> 11, t = row & 2047;
                    int hh = col >> 6, dd = col & 63;
                    ((unsigned short*)C)[(((nb << 4) + hh) * 2048 + t) * 64 + dd] =
                        f2bf(val * sc);
                } else if (mode == 1) {
                    ((float*)C)[(size_t)row * ldc + col] = val;
                } else {
                    ((unsigned short*)C)[(size_t)row * ldc + col] = f2bf(val);
                }
            }
}

// grid 1536: [0,1024) QK fused (m 32 x n 32 tiles) | [1024,1536) V^T = Wv @ X^T
__global__ __launch_bounds__(256) void proj(
    const unsigned short* __restrict__ x16,
    const unsigned short* __restrict__ wq16,
    const unsigned short* __restrict__ wk16,
    const unsigned short* __restrict__ wv16,
    unsigned short* __restrict__ qbuf,
    unsigned short* __restrict__ kbuf,
    unsigned short* __restrict__ vtb)
{
    const int bid = blockIdx.x;
    if (bid < 1024) {
        int m0 = (bid & 31) << 7;
        int n0g = (bid >> 5) << 6;
        if (n0g < 1024)
            gemm_body64(x16, wq16, qbuf, m0, n0g, 0, 0, QSCALE);
        else
            gemm_body64(x16, wk16, kbuf, m0, n0g - 1024, 0, 0, 1.0f);
    } else {
        int v = bid - 1024;   // [0,512): 8 m-tiles x 64 n-tiles
        gemm_body64(wv16, x16, vtb, (v & 7) << 7, (v >> 3) << 6, 2, 4096, 1.0f);
    }
}

// ---------- out = Y @ Wo^T: 64x64 tiles, BK=32 dbuf gload16, fully unrolled ----------
__global__ __launch_bounds__(256) void outp(
    const unsigned short* __restrict__ ybuf,
    const unsigned short* __restrict__ wot,
    float* __restrict__ out)
{
    __shared__ unsigned short sa[2][64 * 32];
    __shared__ unsigned short sb[2][64 * 32];
    const int tid = threadIdx.x, wave = tid >> 6, lane = tid & 63;
    const int l15 = lane & 15, l4 = lane >> 4;
    const int bid = blockIdx.x;
    const int m0 = (bid & 63) << 6, n0 = (bid >> 6) << 6;

    const int r16 = lane >> 2;
    const int gcol = (lane & 3) << 3;
    const unsigned short* Ag = &ybuf[(size_t)(m0 + wave * 16 + r16) * 1024 + gcol];
    const unsigned short* Bg = &wot[(size_t)(n0 + wave * 16 + r16) * 1024 + gcol];
    const int lb = (wave * 16) * 32;

    gload16(Ag, &sa[0][lb]);
    gload16(Bg, &sb[0][lb]);
    __syncthreads();

    f32x4 acc[4] = {};

    #pragma unroll
    for (int kk = 0; kk < 32; ++kk) {
        const int cur = kk & 1;
        if (kk < 31) {
            const int off = (kk + 1) * 32;
            gload16(Ag + off, &sa[1 - cur][lb]);
            gload16(Bg + off, &sb[1 - cur][lb]);
        }
        bf16x8 af = *(const bf16x8*)&sa[cur][(wave * 16 + l15) * 32 + l4 * 8];
        #pragma unroll
        for (int j = 0; j < 4; ++j) {
            bf16x8 bf = *(const bf16x8*)&sb[cur][(j * 16 + l15) * 32 + l4 * 8];
            acc[j] = MFMA_BF16(af, bf, acc[j], 0, 0, 0);
        }
        __syncthreads();
    }

    #pragma unroll
    for (int j = 0; j < 4; ++j)
        #pragma unroll
        for (int r = 0; r < 4; ++r) {
            int row = m0 + wave * 16 + l4 * 4 + r;
            int col = n0 + j * 16 + l15;
            out[(size_t)row * 1024 + col] = acc[j][r];
        }
}

// ---------- flash causal attention: S^T form, pipelined, pair-unrolled parity ----------
__global__ __launch_bounds__(256) void attn(
    const unsigned short* __restrict__ q,
    const unsigned short* __restrict__ k,
    const unsigned short* __restrict__ vt,
    unsigned short* __restrict__ y)
{
    constexpr int P = 72;
    __shared__ unsigned short sk[2][64 * P];   // [s][d]
    __shared__ unsigned short sv[2][64 * P];   // [d][s]
    const int tid = threadIdx.x, wave = tid >> 6, lane = tid & 63;
    const int l15 = lane & 15, l4 = lane >> 4;
    const int bid = blockIdx.x;
    const int qtt = (bid < 512) ? (31 - (bid >> 5)) : ((bid - 512) >> 5);
    const int bh = bid & 31;
    const int nb = bh >> 4, hh = bh & 15;
    const int q0 = qtt << 6;
    const size_t base = (size_t)bh << 17;

    const int r0 = tid >> 3, c0 = (tid & 7) << 3;
    const unsigned short* kg = &k[base + ((size_t)r0 << 6) + c0];
    const unsigned short* vg = &vt[(size_t)((hh << 6) + r0) * 4096 + (nb << 11) + c0];
    const int lk0 = r0 * P + c0, lk1 = (r0 + 32) * P + c0;

    bf16x8 qf[2];
    #pragma unroll
    for (int ks = 0; ks < 2; ++ks)
        qf[ks] = *(const bf16x8*)
            &q[base + (size_t)(q0 + wave * 16 + l15) * 64 + ks * 32 + l4 * 8];

    float l_sum = 0.f;
    f32x4 acc[4] = {};

    const int nst = qtt + 1;

    {
        uint4 ka = *(const uint4*)(kg);
        uint4 kb = *(const uint4*)(kg + (32 << 6));
        uint4 va = *(const uint4*)(vg);
        uint4 vb = *(const uint4*)(vg + 32 * 4096);
        *(uint4*)&sk[0][lk0] = ka;  *(uint4*)&sk[0][lk1] = kb;
        *(uint4*)&sv[0][lk0] = va;  *(uint4*)&sv[0][lk1] = vb;
    }
    __syncthreads();

    // step body; called with LITERAL cur at each site so sk[cur]/sv[cur] bases fold
    auto step = [&](const int cur, const int st, const bool more) {
        uint4 ka, kb, va, vb;
        if (more) {
            const int s1 = (st + 1) << 6;
            ka = *(const uint4*)(kg + ((size_t)s1 << 6));
            kb = *(const uint4*)(kg + ((size_t)(s1 + 32) << 6));
            va = *(const uint4*)(vg + s1);
            vb = *(const uint4*)(vg + 32 * 4096 + s1);
        }

        f32x4 s_acc[4] = {};
        #pragma unroll
        for (int ks = 0; ks < 2; ++ks)
            #pragma unroll
            for (int ns = 0; ns < 4; ++ns) {
                bf16x8 kf = *(const bf16x8*)&sk[cur][(ns * 16 + l15) * P + ks * 32 + l4 * 8];
                s_acc[ns] = MFMA_BF16(kf, qf[ks], s_acc[ns], 0, 0, 0);
            }

        if (st == qtt) {
            const int ql = wave * 16 + l15;
            #pragma unroll
            for (int ns = 0; ns < 4; ++ns) {
                #pragma unroll
                for (int r = 0; r < 4; ++r)
                    if (ns * 16 + l4 * 4 + r > ql) s_acc[ns][r] = -1e30f;
            }
        }

        float pe[4][4];
        #pragma unroll
        for (int ns = 0; ns < 4; ++ns) {
            #pragma unroll
            for (int r = 0; r < 4; ++r) pe[ns][r] = exp2f(s_acc[ns][r]);
            l_sum += (pe[ns][0] + pe[ns][1]) + (pe[ns][2] + pe[ns][3]);
        }

        #pragma unroll
        for (int ks = 0; ks < 2; ++ks) {
            uint4 pw;
            pw.x = pk2t(pe[2 * ks][0], pe[2 * ks][1]);
            pw.y = pk2t(pe[2 * ks][2], pe[2 * ks][3]);
            pw.z = pk2t(pe[2 * ks + 1][0], pe[2 * ks + 1][1]);
            pw.w = pk2t(pe[2 * ks + 1][2], pe[2 * ks + 1][3]);
            bf16x8 pf = *(bf16x8*)&pw;
            #pragma unroll
            for (int ds = 0; ds < 4; ++ds) {
                const unsigned short* vrow =
                    &sv[cur][(ds * 16 + l15) * P + ks * 32 + l4 * 4];
                bf16x4 lo = *(const bf16x4*)vrow;
                bf16x4 hi = *(const bf16x4*)(vrow + 16);
                bf16x8 vf = __builtin_shufflevector(lo, hi, 0, 1, 2, 3, 4, 5, 6, 7);
                acc[ds] = MFMA_BF16(vf, pf, acc[ds], 0, 0, 0);
            }
        }

        if (more) {
            const int nxt = cur ^ 1;
            *(uint4*)&sk[nxt][lk0] = ka;  *(uint4*)&sk[nxt][lk1] = kb;
            *(uint4*)&sv[nxt][lk0] = va;  *(uint4*)&sv[nxt][lk1] = vb;
        }
        __syncthreads();
    };

    int st = 0;
    for (; st + 2 <= nst; st += 2) {
        step(0, st, true);
        step(1, st + 1, (st + 2) < nst);
    }
    if (st < nst) step(0, st, false);

    l_sum += __shfl_xor(l_sum, 16);
    l_sum += __shfl_xor(l_sum, 32);
    const float rl = __builtin_amdgcn_rcpf(l_sum);

    const size_t rowbase =
        ((size_t)((nb << 11) + q0 + wave * 16 + l15) << 10) + (hh << 6) + l4 * 4;
    #pragma unroll
    for (int ds = 0; ds < 4; ++ds) {
        uint2 o;
        o.x = pk2(acc[ds][0] * rl, acc[ds][1] * rl);
        o.y = pk2(acc[ds][2] * rl, acc[ds][3] * rl);
        *(uint2*)&y[rowbase + ds * 16] = o;
    }
}

extern "C" void kernel_launch(void* const* d_in, const int* in_sizes, int n_in,
                              void* d_out, int out_size, void* d_ws, size_t ws_size,
                              hipStream_t stream) {
    const float* x  = (const float*)d_in[0];
    const float* wq = (const float*)d_in[1];
    const float* wk = (const float*)d_in[2];
    const float* wv = (const float*)d_in[3];
    const float* wo = (const float*)d_in[4];
    float* out = (float*)d_out;

    const size_t M1 = 1u << 20;
    unsigned short* x16  = (unsigned short*)d_ws;          // 4M
    unsigned short* wq16 = x16 + 4 * M1;                   // 1M
    unsigned short* wk16 = wq16 + M1;
    unsigned short* wv16 = wk16 + M1;
    unsigned short* wot  = wv16 + M1;                      // 1M
    unsigned short* qbuf = wot + M1;                       // 4M [B,H,T,64]
    unsigned short* kbuf = qbuf + 4 * M1;                  // 4M
    unsigned short* vtb  = kbuf + 4 * M1;                  // 4M [1024][4096]
    unsigned short* ybuf = vtb + 4 * M1;                   // 4M [4096][1024]

    dim3 blk(256);
    prep<<<3840, blk, 0, stream>>>(x, wq, wk, wv, wo, x16, wq16, wk16, wv16, wot);
    proj<<<1536, blk, 0, stream>>>(x16, wq16, wk16, wv16, qbuf, kbuf, vtb);
    attn<<<1024, blk, 0, stream>>>(qbuf, kbuf, vtb, ybuf);
    outp<<<1024, blk, 0, stream>>>(ybuf, wot, out);
}

// Round 15
// 174.437 us; speedup vs baseline: 1.0325x; 1.0325x over previous
//
#include <hip/hip_runtime.h>

// B=2, T=2048, C=1024, H=16, DQK=DV=64. Inputs fp32, output fp32, bf16 MFMA inside.

typedef short bf16x4 __attribute__((ext_vector_type(4)));
typedef short bf16x8 __attribute__((ext_vector_type(8)));
typedef float f32x4 __attribute__((ext_vector_type(4)));

#define MFMA_BF16 __builtin_amdgcn_mfma_f32_16x16x32_bf16

// log2(e)/8: Q pre-scale so softmax runs in base-2 domain (exp2 = bare v_exp_f32)
#define QSCALE 0.18033688011112042f

__device__ __forceinline__ unsigned short f2bf(float f) {
    union { float f; unsigned u; } un; un.f = f;
    unsigned r = un.u + 0x7fffu + ((un.u >> 16) & 1u);  // RNE
    return (unsigned short)(r >> 16);
}
__device__ __forceinline__ unsigned pk2(float a, float b) {
    return (unsigned)f2bf(a) | ((unsigned)f2bf(b) << 16);
}
// truncating pack of two floats into packed bf16x2
__device__ __forceinline__ unsigned pk2t(float a, float b) {
    union { float f; unsigned u; } ua, ub; ua.f = a; ub.f = b;
    return (ua.u >> 16) | (ub.u & 0xffff0000u);
}
__device__ __forceinline__ void gload16(const void* g, void* l) {
    __builtin_amdgcn_global_load_lds(
        (const __attribute__((address_space(1))) unsigned int*)g,
        (__attribute__((address_space(3))) unsigned int*)l, 16, 0, 0);
}

// ---------- fused prep: x/wq/wk/wv fp32->bf16, wo fp32->bf16 transposed ----------
__global__ __launch_bounds__(256) void prep(
    const float* __restrict__ x, const float* __restrict__ wq,
    const float* __restrict__ wk, const float* __restrict__ wv,
    const float* __restrict__ wo,
    unsigned short* __restrict__ x16, unsigned short* __restrict__ wq16,
    unsigned short* __restrict__ wk16, unsigned short* __restrict__ wv16,
    unsigned short* __restrict__ wot)
{
    const int bid = blockIdx.x;
    if (bid < 3584) {
        const float* s; unsigned short* d; int off;
        if (bid < 2048)      { s = x;  d = x16;  off = bid * 2048; }
        else if (bid < 2560) { s = wq; d = wq16; off = (bid - 2048) * 2048; }
        else if (bid < 3072) { s = wk; d = wk16; off = (bid - 2560) * 2048; }
        else                 { s = wv; d = wv16; off = (bid - 3072) * 2048; }
        int i = off + threadIdx.x * 8;
        float4 f0 = *(const float4*)&s[i], f1 = *(const float4*)&s[i + 4];
        uint4 o;
        o.x = pk2(f0.x, f0.y); o.y = pk2(f0.z, f0.w);
        o.z = pk2(f1.x, f1.y); o.w = pk2(f1.z, f1.w);
        *(uint4*)&d[i] = o;
    } else {
        // wo [K=1024][N=1024] -> wot [N][K] bf16
        __shared__ unsigned short t[64 * 72];
        const int b2 = bid - 3584;
        const int k0 = (b2 & 15) << 6, n0 = (b2 >> 4) << 6;
        const int r = threadIdx.x >> 2, cg = (threadIdx.x & 3) << 4;
        const float* src = &wo[(k0 + r) * 1024 + n0 + cg];
        #pragma unroll
        for (int j = 0; j < 16; j += 4) {
            float4 f = *(const float4*)&src[j];
            t[(cg + j + 0) * 72 + r] = f2bf(f.x);
            t[(cg + j + 1) * 72 + r] = f2bf(f.y);
            t[(cg + j + 2) * 72 + r] = f2bf(f.z);
            t[(cg + j + 3) * 72 + r] = f2bf(f.w);
        }
        __syncthreads();
        unsigned short* dst = &wot[(n0 + r) * 1024 + k0 + cg];
        unsigned short* tr = &t[r * 72 + cg];
        unsigned v[16];
        #pragma unroll
        for (int j = 0; j < 16; ++j) v[j] = tr[j];
        uint4 o0, o1;
        o0.x = v[0] | (v[1] << 16);   o0.y = v[2] | (v[3] << 16);
        o0.z = v[4] | (v[5] << 16);   o0.w = v[6] | (v[7] << 16);
        o1.x = v[8] | (v[9] << 16);   o1.y = v[10] | (v[11] << 16);
        o1.z = v[12] | (v[13] << 16); o1.w = v[14] | (v[15] << 16);
        *(uint4*)&dst[0] = o0;
        *(uint4*)&dst[8] = o1;
    }
}

// ---------- 128x128 bf16 GEMM, K=1024: BK=32 dbuf gload16, fully unrolled ----------
// R13 config (proven best: R14's 128x64 raised staging traffic 1.5x and regressed;
// proj is pipe-throughput bound, occupancy-neutral).
// mode 2 = vtb store WITH sigma permutation: within each 32-col block, value at
// s goes to index i = ((s>>2)&3)*8 + ((s>>4)&1)*4 + (s&3), so attn's PV A-frag
// (slot j needs s=(j>>2)*16+l4*4+(j&3)) reads one contiguous b128 at l4*8.
__device__ __forceinline__ void gemm_body(
    const unsigned short* __restrict__ A, const unsigned short* __restrict__ Bm,
    void* __restrict__ C, int m0, int n0, int mode, int ldc, float sc)
{
    __shared__ unsigned short sa[2][128 * 32];
    __shared__ unsigned short sb[2][128 * 32];
    const int tid = threadIdx.x, wave = tid >> 6, lane = tid & 63;
    const int l15 = lane & 15, l4 = lane >> 4;
    const int wm = (wave >> 1) << 6, wn = (wave & 1) << 6;

    const int r16 = lane >> 2;             // 0..15
    const int gcol = (lane & 3) << 3;      // 0,8,16,24
    const unsigned short* Ag0 = &A[(size_t)(m0 + wave * 16 + r16) * 1024 + gcol];
    const unsigned short* Ag1 = Ag0 + (size_t)64 * 1024;
    const unsigned short* Bg0 = &Bm[(size_t)(n0 + wave * 16 + r16) * 1024 + gcol];
    const unsigned short* Bg1 = Bg0 + (size_t)64 * 1024;
    const int lb0 = (wave * 16) * 32;      // wave-uniform LDS bases (elements)
    const int lb1 = (64 + wave * 16) * 32;

    gload16(Ag0, &sa[0][lb0]);
    gload16(Ag1, &sa[0][lb1]);
    gload16(Bg0, &sb[0][lb0]);
    gload16(Bg1, &sb[0][lb1]);
    __syncthreads();

    f32x4 acc[4][4] = {};

    #pragma unroll
    for (int kk = 0; kk < 32; ++kk) {
        const int cur = kk & 1;
        if (kk < 31) {
            const int off = (kk + 1) * 32;
            const int nxt = 1 - cur;
            gload16(Ag0 + off, &sa[nxt][lb0]);
            gload16(Ag1 + off, &sa[nxt][lb1]);
            gload16(Bg0 + off, &sb[nxt][lb0]);
            gload16(Bg1 + off, &sb[nxt][lb1]);
        }
        bf16x8 af[4], bf4[4];
        #pragma unroll
        for (int i = 0; i < 4; ++i)
            af[i] = *(const bf16x8*)&sa[cur][(wm + i * 16 + l15) * 32 + l4 * 8];
        #pragma unroll
        for (int j = 0; j < 4; ++j)
            bf4[j] = *(const bf16x8*)&sb[cur][(wn + j * 16 + l15) * 32 + l4 * 8];
        #pragma unroll
        for (int i = 0; i < 4; ++i)
            #pragma unroll
            for (int j = 0; j < 4; ++j)
                acc[i][j] = MFMA_BF16(af[i], bf4[j], acc[i][j], 0, 0, 0);
        __syncthreads();   // next-slab loads have flown during the MFMAs above
    }

    #pragma unroll
    for (int i = 0; i < 4; ++i)
        #pragma unroll
        for (int j = 0; j < 4; ++j)
            #pragma unroll
            for (int r = 0; r < 4; ++r) {
                int row = m0 + wm + i * 16 + l4 * 4 + r;
                int col = n0 + wn + j * 16 + l15;
                float val = acc[i][j][r];
                if (mode == 0) {
                    int nb = row >> 11, t = row & 2047;
                    int hh = col >> 6, dd = col & 63;
                    ((unsigned short*)C)[(((nb << 4) + hh) * 2048 + t) * 64 + dd] =
                        f2bf(val * sc);
                } else if (mode == 1) {
                    ((float*)C)[(size_t)row * ldc + col] = val;
                } else {
                    // sigma permutation within each 32-col block (see header)
                    int s = col & 31;
                    int cp = (col & ~31) | (((s >> 2) & 3) << 3)
                                         | (((s >> 4) & 1) << 2) | (s & 3);
                    ((unsigned short*)C)[(size_t)row * ldc + cp] = f2bf(val);
                }
            }
}

// grid 768: [0,512) QK fused | [512,768) V^T = Wv @ X^T (sigma-permuted cols)
__global__ __launch_bounds__(256) void proj(
    const unsigned short* __restrict__ x16,
    const unsigned short* __restrict__ wq16,
    const unsigned short* __restrict__ wk16,
    const unsigned short* __restrict__ wv16,
    unsigned short* __restrict__ qbuf,
    unsigned short* __restrict__ kbuf,
    unsigned short* __restrict__ vtb)
{
    const int bid = blockIdx.x;
    if (bid < 512) {
        int m0 = (bid & 31) << 7;
        int n0g = (bid >> 5) << 7;
        if (n0g < 1024)
            gemm_body(x16, wq16, qbuf, m0, n0g, 0, 0, QSCALE);
        else
            gemm_body(x16, wk16, kbuf, m0, n0g - 1024, 0, 0, 1.0f);
    } else {
        int v = bid - 512;
        gemm_body(wv16, x16, vtb, (v & 7) << 7, (v >> 3) << 7, 2, 4096, 1.0f);
    }
}

// ---------- out = Y @ Wo^T: 64x64 tiles, BK=32 dbuf gload16, fully unrolled ----------
__global__ __launch_bounds__(256) void outp(
    const unsigned short* __restrict__ ybuf,
    const unsigned short* __restrict__ wot,
    float* __restrict__ out)
{
    __shared__ unsigned short sa[2][64 * 32];
    __shared__ unsigned short sb[2][64 * 32];
    const int tid = threadIdx.x, wave = tid >> 6, lane = tid & 63;
    const int l15 = lane & 15, l4 = lane >> 4;
    const int bid = blockIdx.x;
    const int m0 = (bid & 63) << 6, n0 = (bid >> 6) << 6;

    const int r16 = lane >> 2;
    const int gcol = (lane & 3) << 3;
    const unsigned short* Ag = &ybuf[(size_t)(m0 + wave * 16 + r16) * 1024 + gcol];
    const unsigned short* Bg = &wot[(size_t)(n0 + wave * 16 + r16) * 1024 + gcol];
    const int lb = (wave * 16) * 32;

    gload16(Ag, &sa[0][lb]);
    gload16(Bg, &sb[0][lb]);
    __syncthreads();

    f32x4 acc[4] = {};

    #pragma unroll
    for (int kk = 0; kk < 32; ++kk) {
        const int cur = kk & 1;
        if (kk < 31) {
            const int off = (kk + 1) * 32;
            gload16(Ag + off, &sa[1 - cur][lb]);
            gload16(Bg + off, &sb[1 - cur][lb]);
        }
        bf16x8 af = *(const bf16x8*)&sa[cur][(wave * 16 + l15) * 32 + l4 * 8];
        #pragma unroll
        for (int j = 0; j < 4; ++j) {
            bf16x8 bf = *(const bf16x8*)&sb[cur][(j * 16 + l15) * 32 + l4 * 8];
            acc[j] = MFMA_BF16(af, bf, acc[j], 0, 0, 0);
        }
        __syncthreads();
    }

    #pragma unroll
    for (int j = 0; j < 4; ++j)
        #pragma unroll
        for (int r = 0; r < 4; ++r) {
            int row = m0 + wave * 16 + l4 * 4 + r;
            int col = n0 + j * 16 + l15;
            out[(size_t)row * 1024 + col] = acc[j][r];
        }
}

// ---------- flash causal attention: S^T form, pipelined, pair-unrolled parity ----------
// vtb is sigma-permuted by proj, so the PV A-frag is ONE contiguous b128 read.
__global__ __launch_bounds__(256) void attn(
    const unsigned short* __restrict__ q,
    const unsigned short* __restrict__ k,
    const unsigned short* __restrict__ vt,
    unsigned short* __restrict__ y)
{
    constexpr int P = 72;
    __shared__ unsigned short sk[2][64 * P];   // [s][d]
    __shared__ unsigned short sv[2][64 * P];   // [d][s-permuted]
    const int tid = threadIdx.x, wave = tid >> 6, lane = tid & 63;
    const int l15 = lane & 15, l4 = lane >> 4;
    const int bid = blockIdx.x;
    const int qtt = (bid < 512) ? (31 - (bid >> 5)) : ((bid - 512) >> 5);
    const int bh = bid & 31;
    const int nb = bh >> 4, hh = bh & 15;
    const int q0 = qtt << 6;
    const size_t base = (size_t)bh << 17;

    const int r0 = tid >> 3, c0 = (tid & 7) << 3;
    const unsigned short* kg = &k[base + ((size_t)r0 << 6) + c0];
    const unsigned short* vg = &vt[(size_t)((hh << 6) + r0) * 4096 + (nb << 11) + c0];
    const int lk0 = r0 * P + c0, lk1 = (r0 + 32) * P + c0;

    bf16x8 qf[2];
    #pragma unroll
    for (int ks = 0; ks < 2; ++ks)
        qf[ks] = *(const bf16x8*)
            &q[base + (size_t)(q0 + wave * 16 + l15) * 64 + ks * 32 + l4 * 8];

    float l_sum = 0.f;
    f32x4 acc[4] = {};

    const int nst = qtt + 1;

    {
        uint4 ka = *(const uint4*)(kg);
        uint4 kb = *(const uint4*)(kg + (32 << 6));
        uint4 va = *(const uint4*)(vg);
        uint4 vb = *(const uint4*)(vg + 32 * 4096);
        *(uint4*)&sk[0][lk0] = ka;  *(uint4*)&sk[0][lk1] = kb;
        *(uint4*)&sv[0][lk0] = va;  *(uint4*)&sv[0][lk1] = vb;
    }
    __syncthreads();

    // step body; called with LITERAL cur at each site so sk[cur]/sv[cur] bases fold
    auto step = [&](const int cur, const int st, const bool more) {
        uint4 ka, kb, va, vb;
        if (more) {
            const int s1 = (st + 1) << 6;
            ka = *(const uint4*)(kg + ((size_t)s1 << 6));
            kb = *(const uint4*)(kg + ((size_t)(s1 + 32) << 6));
            va = *(const uint4*)(vg + s1);
            vb = *(const uint4*)(vg + 32 * 4096 + s1);
        }

        f32x4 s_acc[4] = {};
        #pragma unroll
        for (int ks = 0; ks < 2; ++ks)
            #pragma unroll
            for (int ns = 0; ns < 4; ++ns) {
                bf16x8 kf = *(const bf16x8*)&sk[cur][(ns * 16 + l15) * P + ks * 32 + l4 * 8];
                s_acc[ns] = MFMA_BF16(kf, qf[ks], s_acc[ns], 0, 0, 0);
            }

        if (st == qtt) {
            const int ql = wave * 16 + l15;
            #pragma unroll
            for (int ns = 0; ns < 4; ++ns) {
                #pragma unroll
                for (int r = 0; r < 4; ++r)
                    if (ns * 16 + l4 * 4 + r > ql) s_acc[ns][r] = -1e30f;
            }
        }

        float pe[4][4];
        #pragma unroll
        for (int ns = 0; ns < 4; ++ns) {
            #pragma unroll
            for (int r = 0; r < 4; ++r) pe[ns][r] = exp2f(s_acc[ns][r]);
            l_sum += (pe[ns][0] + pe[ns][1]) + (pe[ns][2] + pe[ns][3]);
        }

        #pragma unroll
        for (int ks = 0; ks < 2; ++ks) {
            uint4 pw;
            pw.x = pk2t(pe[2 * ks][0], pe[2 * ks][1]);
            pw.y = pk2t(pe[2 * ks][2], pe[2 * ks][3]);
            pw.z = pk2t(pe[2 * ks + 1][0], pe[2 * ks + 1][1]);
            pw.w = pk2t(pe[2 * ks + 1][2], pe[2 * ks + 1][3]);
            bf16x8 pf = *(bf16x8*)&pw;
            #pragma unroll
            for (int ds = 0; ds < 4; ++ds) {
                // sigma-permuted vtb: contiguous b128
                bf16x8 vf = *(const bf16x8*)
                    &sv[cur][(ds * 16 + l15) * P + ks * 32 + l4 * 8];
                acc[ds] = MFMA_BF16(vf, pf, acc[ds], 0, 0, 0);
            }
        }

        if (more) {
            const int nxt = cur ^ 1;
            *(uint4*)&sk[nxt][lk0] = ka;  *(uint4*)&sk[nxt][lk1] = kb;
            *(uint4*)&sv[nxt][lk0] = va;  *(uint4*)&sv[nxt][lk1] = vb;
        }
        __syncthreads();
    };

    int st = 0;
    for (; st + 2 <= nst; st += 2) {
        step(0, st, true);
        step(1, st + 1, (st + 2) < nst);
    }
    if (st < nst) step(0, st, false);

    l_sum += __shfl_xor(l_sum, 16);
    l_sum += __shfl_xor(l_sum, 32);
    const float rl = __builtin_amdgcn_rcpf(l_sum);

    const size_t rowbase =
        ((size_t)((nb << 11) + q0 + wave * 16 + l15) << 10) + (hh << 6) + l4 * 4;
    #pragma unroll
    for (int ds = 0; ds < 4; ++ds) {
        uint2 o;
        o.x = pk2(acc[ds][0] * rl, acc[ds][1] * rl);
        o.y = pk2(acc[ds][2] * rl, acc[ds][3] * rl);
        *(uint2*)&y[rowbase + ds * 16] = o;
    }
}

extern "C" void kernel_launch(void* const* d_in, const int* in_sizes, int n_in,
                              void* d_out, int out_size, void* d_ws, size_t ws_size,
                              hipStream_t stream) {
    const float* x  = (const float*)d_in[0];
    const float* wq = (const float*)d_in[1];
    const float* wk = (const float*)d_in[2];
    const float* wv = (const float*)d_in[3];
    const float* wo = (const float*)d_in[4];
    float* out = (float*)d_out;

    const size_t M1 = 1u << 20;
    unsigned short* x16  = (unsigned short*)d_ws;          // 4M
    unsigned short* wq16 = x16 + 4 * M1;                   // 1M
    unsigned short* wk16 = wq16 + M1;
    unsigned short* wv16 = wk16 + M1;
    unsigned short* wot  = wv16 + M1;                      // 1M
    unsigned short* qbuf = wot + M1;                       // 4M [B,H,T,64]
    unsigned short* kbuf = qbuf + 4 * M1;                  // 4M
    unsigned short* vtb  = kbuf + 4 * M1;                  // 4M [1024][4096] sigma-perm
    unsigned short* ybuf = vtb + 4 * M1;                   // 4M [4096][1024]

    dim3 blk(256);
    prep<<<3840, blk, 0, stream>>>(x, wq, wk, wv, wo, x16, wq16, wk16, wv16, wot);
    proj<<<768, blk, 0, stream>>>(x16, wq16, wk16, wv16, qbuf, kbuf, vtb);
    attn<<<1024, blk, 0, stream>>>(qbuf, kbuf, vtb, ybuf);
    outp<<<1024, blk, 0, stream>>>(ybuf, wot, out);
}

// Round 16
// 170.888 us; speedup vs baseline: 1.0540x; 1.0208x over previous
//
#include <hip/hip_runtime.h>

// B=2, T=2048, C=1024, H=16, DQK=DV=64. Inputs fp32, output fp32, bf16 MFMA inside.

typedef short bf16x4 __attribute__((ext_vector_type(4)));
typedef short bf16x8 __attribute__((ext_vector_type(8)));
typedef float f32x4 __attribute__((ext_vector_type(4)));

#define MFMA_BF16 __builtin_amdgcn_mfma_f32_16x16x32_bf16

// log2(e)/8: Q pre-scale so softmax runs in base-2 domain (exp2 = bare v_exp_f32)
#define QSCALE 0.18033688011112042f

__device__ __forceinline__ unsigned short f2bf(float f) {
    union { float f; unsigned u; } un; un.f = f;
    unsigned r = un.u + 0x7fffu + ((un.u >> 16) & 1u);  // RNE
    return (unsigned short)(r >> 16);
}
__device__ __forceinline__ unsigned pk2(float a, float b) {
    return (unsigned)f2bf(a) | ((unsigned)f2bf(b) << 16);
}
// truncating pack of two floats into packed bf16x2
__device__ __forceinline__ unsigned pk2t(float a, float b) {
    union { float f; unsigned u; } ua, ub; ua.f = a; ub.f = b;
    return (ua.u >> 16) | (ub.u & 0xffff0000u);
}
__device__ __forceinline__ void gload16(const void* g, void* l) {
    __builtin_amdgcn_global_load_lds(
        (const __attribute__((address_space(1))) unsigned int*)g,
        (__attribute__((address_space(3))) unsigned int*)l, 16, 0, 0);
}

// ---------- fused prep: x/wq/wk/wv fp32->bf16, wo fp32->bf16 transposed ----------
__global__ __launch_bounds__(256) void prep(
    const float* __restrict__ x, const float* __restrict__ wq,
    const float* __restrict__ wk, const float* __restrict__ wv,
    const float* __restrict__ wo,
    unsigned short* __restrict__ x16, unsigned short* __restrict__ wq16,
    unsigned short* __restrict__ wk16, unsigned short* __restrict__ wv16,
    unsigned short* __restrict__ wot)
{
    const int bid = blockIdx.x;
    if (bid < 3584) {
        const float* s; unsigned short* d; int off;
        if (bid < 2048)      { s = x;  d = x16;  off = bid * 2048; }
        else if (bid < 2560) { s = wq; d = wq16; off = (bid - 2048) * 2048; }
        else if (bid < 3072) { s = wk; d = wk16; off = (bid - 2560) * 2048; }
        else                 { s = wv; d = wv16; off = (bid - 3072) * 2048; }
        int i = off + threadIdx.x * 8;
        float4 f0 = *(const float4*)&s[i], f1 = *(const float4*)&s[i + 4];
        uint4 o;
        o.x = pk2(f0.x, f0.y); o.y = pk2(f0.z, f0.w);
        o.z = pk2(f1.x, f1.y); o.w = pk2(f1.z, f1.w);
        *(uint4*)&d[i] = o;
    } else {
        // wo [K=1024][N=1024] -> wot [N][K] bf16
        __shared__ unsigned short t[64 * 72];
        const int b2 = bid - 3584;
        const int k0 = (b2 & 15) << 6, n0 = (b2 >> 4) << 6;
        const int r = threadIdx.x >> 2, cg = (threadIdx.x & 3) << 4;
        const float* src = &wo[(k0 + r) * 1024 + n0 + cg];
        #pragma unroll
        for (int j = 0; j < 16; j += 4) {
            float4 f = *(const float4*)&src[j];
            t[(cg + j + 0) * 72 + r] = f2bf(f.x);
            t[(cg + j + 1) * 72 + r] = f2bf(f.y);
            t[(cg + j + 2) * 72 + r] = f2bf(f.z);
            t[(cg + j + 3) * 72 + r] = f2bf(f.w);
        }
        __syncthreads();
        unsigned short* dst = &wot[(n0 + r) * 1024 + k0 + cg];
        unsigned short* tr = &t[r * 72 + cg];
        unsigned v[16];
        #pragma unroll
        for (int j = 0; j < 16; ++j) v[j] = tr[j];
        uint4 o0, o1;
        o0.x = v[0] | (v[1] << 16);   o0.y = v[2] | (v[3] << 16);
        o0.z = v[4] | (v[5] << 16);   o0.w = v[6] | (v[7] << 16);
        o1.x = v[8] | (v[9] << 16);   o1.y = v[10] | (v[11] << 16);
        o1.z = v[12] | (v[13] << 16); o1.w = v[14] | (v[15] << 16);
        *(uint4*)&dst[0] = o0;
        *(uint4*)&dst[8] = o1;
    }
}

// ---------- 128x128 bf16 GEMM, K=1024: BK=32 dbuf gload16, fully unrolled ----------
// R16: data-side XOR bank swizzle. The 64B row stride makes plain ds_read_b128
// 4-way bank-conflicted (R13/R15: 191 conflict-cyc/block-slab). global_load_lds
// deposits are HW-fixed (lane i -> row i>>2, chunk i&3), so we permute WHICH
// global chunk each lane fetches: G-chunk = (lane&3) ^ ((r16>>1)&3). Then
// LDS[r][c] = G[r][c ^ ((r>>1)&3)]; readers use chunk l4 ^ ((l15>>1)&3).
// Quad map becomes 2-way everywhere = free (m136). Coalescing preserved
// (4-lane groups still cover one 64B row). Fragment data bit-identical.
// mode 2 = vtb store WITH sigma permutation (R15): within each 32-col block,
// s -> ((s>>2)&3)*8 + ((s>>4)&1)*4 + (s&3) so attn's PV A-frag is one b128.
__device__ __forceinline__ void gemm_body(
    const unsigned short* __restrict__ A, const unsigned short* __restrict__ Bm,
    void* __restrict__ C, int m0, int n0, int mode, int ldc, float sc)
{
    __shared__ unsigned short sa[2][128 * 32];
    __shared__ unsigned short sb[2][128 * 32];
    const int tid = threadIdx.x, wave = tid >> 6, lane = tid & 63;
    const int l15 = lane & 15, l4 = lane >> 4;
    const int wm = (wave >> 1) << 6, wn = (wave & 1) << 6;

    const int r16 = lane >> 2;                               // 0..15
    const int gcol = (((lane & 3) ^ ((r16 >> 1) & 3)) << 3); // swizzled 16B chunk
    const int rcol = (l4 ^ ((l15 >> 1) & 3)) << 3;           // read-side chunk
    const unsigned short* Ag0 = &A[(size_t)(m0 + wave * 16 + r16) * 1024 + gcol];
    const unsigned short* Ag1 = Ag0 + (size_t)64 * 1024;
    const unsigned short* Bg0 = &Bm[(size_t)(n0 + wave * 16 + r16) * 1024 + gcol];
    const unsigned short* Bg1 = Bg0 + (size_t)64 * 1024;
    const int lb0 = (wave * 16) * 32;      // wave-uniform LDS bases (elements)
    const int lb1 = (64 + wave * 16) * 32;

    gload16(Ag0, &sa[0][lb0]);
    gload16(Ag1, &sa[0][lb1]);
    gload16(Bg0, &sb[0][lb0]);
    gload16(Bg1, &sb[0][lb1]);
    __syncthreads();

    f32x4 acc[4][4] = {};

    #pragma unroll
    for (int kk = 0; kk < 32; ++kk) {
        const int cur = kk & 1;
        if (kk < 31) {
            const int off = (kk + 1) * 32;
            const int nxt = 1 - cur;
            gload16(Ag0 + off, &sa[nxt][lb0]);
            gload16(Ag1 + off, &sa[nxt][lb1]);
            gload16(Bg0 + off, &sb[nxt][lb0]);
            gload16(Bg1 + off, &sb[nxt][lb1]);
        }
        bf16x8 af[4], bf4[4];
        #pragma unroll
        for (int i = 0; i < 4; ++i)
            af[i] = *(const bf16x8*)&sa[cur][(wm + i * 16 + l15) * 32 + rcol];
        #pragma unroll
        for (int j = 0; j < 4; ++j)
            bf4[j] = *(const bf16x8*)&sb[cur][(wn + j * 16 + l15) * 32 + rcol];
        #pragma unroll
        for (int i = 0; i < 4; ++i)
            #pragma unroll
            for (int j = 0; j < 4; ++j)
                acc[i][j] = MFMA_BF16(af[i], bf4[j], acc[i][j], 0, 0, 0);
        __syncthreads();   // next-slab loads have flown during the MFMAs above
    }

    #pragma unroll
    for (int i = 0; i < 4; ++i)
        #pragma unroll
        for (int j = 0; j < 4; ++j)
            #pragma unroll
            for (int r = 0; r < 4; ++r) {
                int row = m0 + wm + i * 16 + l4 * 4 + r;
                int col = n0 + wn + j * 16 + l15;
                float val = acc[i][j][r];
                if (mode == 0) {
                    int nb = row >> 11, t = row & 2047;
                    int hh = col >> 6, dd = col & 63;
                    ((unsigned short*)C)[(((nb << 4) + hh) * 2048 + t) * 64 + dd] =
                        f2bf(val * sc);
                } else if (mode == 1) {
                    ((float*)C)[(size_t)row * ldc + col] = val;
                } else {
                    // sigma permutation within each 32-col block (see header)
                    int s = col & 31;
                    int cp = (col & ~31) | (((s >> 2) & 3) << 3)
                                         | (((s >> 4) & 1) << 2) | (s & 3);
                    ((unsigned short*)C)[(size_t)row * ldc + cp] = f2bf(val);
                }
            }
}

// grid 768: [0,512) QK fused | [512,768) V^T = Wv @ X^T (sigma-permuted cols)
__global__ __launch_bounds__(256) void proj(
    const unsigned short* __restrict__ x16,
    const unsigned short* __restrict__ wq16,
    const unsigned short* __restrict__ wk16,
    const unsigned short* __restrict__ wv16,
    unsigned short* __restrict__ qbuf,
    unsigned short* __restrict__ kbuf,
    unsigned short* __restrict__ vtb)
{
    const int bid = blockIdx.x;
    if (bid < 512) {
        int m0 = (bid & 31) << 7;
        int n0g = (bid >> 5) << 7;
        if (n0g < 1024)
            gemm_body(x16, wq16, qbuf, m0, n0g, 0, 0, QSCALE);
        else
            gemm_body(x16, wk16, kbuf, m0, n0g - 1024, 0, 0, 1.0f);
    } else {
        int v = bid - 512;
        gemm_body(wv16, x16, vtb, (v & 7) << 7, (v >> 3) << 7, 2, 4096, 1.0f);
    }
}

// ---------- out = Y @ Wo^T: 64x64 tiles, BK=32 dbuf gload16, swizzled ----------
__global__ __launch_bounds__(256) void outp(
    const unsigned short* __restrict__ ybuf,
    const unsigned short* __restrict__ wot,
    float* __restrict__ out)
{
    __shared__ unsigned short sa[2][64 * 32];
    __shared__ unsigned short sb[2][64 * 32];
    const int tid = threadIdx.x, wave = tid >> 6, lane = tid & 63;
    const int l15 = lane & 15, l4 = lane >> 4;
    const int bid = blockIdx.x;
    const int m0 = (bid & 63) << 6, n0 = (bid >> 6) << 6;

    const int r16 = lane >> 2;
    const int gcol = (((lane & 3) ^ ((r16 >> 1) & 3)) << 3);
    const int rcol = (l4 ^ ((l15 >> 1) & 3)) << 3;
    const unsigned short* Ag = &ybuf[(size_t)(m0 + wave * 16 + r16) * 1024 + gcol];
    const unsigned short* Bg = &wot[(size_t)(n0 + wave * 16 + r16) * 1024 + gcol];
    const int lb = (wave * 16) * 32;

    gload16(Ag, &sa[0][lb]);
    gload16(Bg, &sb[0][lb]);
    __syncthreads();

    f32x4 acc[4] = {};

    #pragma unroll
    for (int kk = 0; kk < 32; ++kk) {
        const int cur = kk & 1;
        if (kk < 31) {
            const int off = (kk + 1) * 32;
            gload16(Ag + off, &sa[1 - cur][lb]);
            gload16(Bg + off, &sb[1 - cur][lb]);
        }
        bf16x8 af = *(const bf16x8*)&sa[cur][(wave * 16 + l15) * 32 + rcol];
        #pragma unroll
        for (int j = 0; j < 4; ++j) {
            bf16x8 bf = *(const bf16x8*)&sb[cur][(j * 16 + l15) * 32 + rcol];
            acc[j] = MFMA_BF16(af, bf, acc[j], 0, 0, 0);
        }
        __syncthreads();
    }

    #pragma unroll
    for (int j = 0; j < 4; ++j)
        #pragma unroll
        for (int r = 0; r < 4; ++r) {
            int row = m0 + wave * 16 + l4 * 4 + r;
            int col = n0 + j * 16 + l15;
            out[(size_t)row * 1024 + col] = acc[j][r];
        }
}

// ---------- flash causal attention: S^T form, pipelined, pair-unrolled parity ----------
// vtb is sigma-permuted by proj, so the PV A-frag is ONE contiguous b128 read.
__global__ __launch_bounds__(256) void attn(
    const unsigned short* __restrict__ q,
    const unsigned short* __restrict__ k,
    const unsigned short* __restrict__ vt,
    unsigned short* __restrict__ y)
{
    constexpr int P = 72;
    __shared__ unsigned short sk[2][64 * P];   // [s][d]
    __shared__ unsigned short sv[2][64 * P];   // [d][s-permuted]
    const int tid = threadIdx.x, wave = tid >> 6, lane = tid & 63;
    const int l15 = lane & 15, l4 = lane >> 4;
    const int bid = blockIdx.x;
    const int qtt = (bid < 512) ? (31 - (bid >> 5)) : ((bid - 512) >> 5);
    const int bh = bid & 31;
    const int nb = bh >> 4, hh = bh & 15;
    const int q0 = qtt << 6;
    const size_t base = (size_t)bh << 17;

    const int r0 = tid >> 3, c0 = (tid & 7) << 3;
    const unsigned short* kg = &k[base + ((size_t)r0 << 6) + c0];
    const unsigned short* vg = &vt[(size_t)((hh << 6) + r0) * 4096 + (nb << 11) + c0];
    const int lk0 = r0 * P + c0, lk1 = (r0 + 32) * P + c0;

    bf16x8 qf[2];
    #pragma unroll
    for (int ks = 0; ks < 2; ++ks)
        qf[ks] = *(const bf16x8*)
            &q[base + (size_t)(q0 + wave * 16 + l15) * 64 + ks * 32 + l4 * 8];

    float l_sum = 0.f;
    f32x4 acc[4] = {};

    const int nst = qtt + 1;

    {
        uint4 ka = *(const uint4*)(kg);
        uint4 kb = *(const uint4*)(kg + (32 << 6));
        uint4 va = *(const uint4*)(vg);
        uint4 vb = *(const uint4*)(vg + 32 * 4096);
        *(uint4*)&sk[0][lk0] = ka;  *(uint4*)&sk[0][lk1] = kb;
        *(uint4*)&sv[0][lk0] = va;  *(uint4*)&sv[0][lk1] = vb;
    }
    __syncthreads();

    // step body; called with LITERAL cur at each site so sk[cur]/sv[cur] bases fold
    auto step = [&](const int cur, const int st, const bool more) {
        uint4 ka, kb, va, vb;
        if (more) {
            const int s1 = (st + 1) << 6;
            ka = *(const uint4*)(kg + ((size_t)s1 << 6));
            kb = *(const uint4*)(kg + ((size_t)(s1 + 32) << 6));
            va = *(const uint4*)(vg + s1);
            vb = *(const uint4*)(vg + 32 * 4096 + s1);
        }

        f32x4 s_acc[4] = {};
        #pragma unroll
        for (int ks = 0; ks < 2; ++ks)
            #pragma unroll
            for (int ns = 0; ns < 4; ++ns) {
                bf16x8 kf = *(const bf16x8*)&sk[cur][(ns * 16 + l15) * P + ks * 32 + l4 * 8];
                s_acc[ns] = MFMA_BF16(kf, qf[ks], s_acc[ns], 0, 0, 0);
            }

        if (st == qtt) {
            const int ql = wave * 16 + l15;
            #pragma unroll
            for (int ns = 0; ns < 4; ++ns) {
                #pragma unroll
                for (int r = 0; r < 4; ++r)
                    if (ns * 16 + l4 * 4 + r > ql) s_acc[ns][r] = -1e30f;
            }
        }

        float pe[4][4];
        #pragma unroll
        for (int ns = 0; ns < 4; ++ns) {
            #pragma unroll
            for (int r = 0; r < 4; ++r) pe[ns][r] = exp2f(s_acc[ns][r]);
            l_sum += (pe[ns][0] + pe[ns][1]) + (pe[ns][2] + pe[ns][3]);
        }

        #pragma unroll
        for (int ks = 0; ks < 2; ++ks) {
            uint4 pw;
            pw.x = pk2t(pe[2 * ks][0], pe[2 * ks][1]);
            pw.y = pk2t(pe[2 * ks][2], pe[2 * ks][3]);
            pw.z = pk2t(pe[2 * ks + 1][0], pe[2 * ks + 1][1]);
            pw.w = pk2t(pe[2 * ks + 1][2], pe[2 * ks + 1][3]);
            bf16x8 pf = *(bf16x8*)&pw;
            #pragma unroll
            for (int ds = 0; ds < 4; ++ds) {
                // sigma-permuted vtb: contiguous b128
                bf16x8 vf = *(const bf16x8*)
                    &sv[cur][(ds * 16 + l15) * P + ks * 32 + l4 * 8];
                acc[ds] = MFMA_BF16(vf, pf, acc[ds], 0, 0, 0);
            }
        }

        if (more) {
            const int nxt = cur ^ 1;
            *(uint4*)&sk[nxt][lk0] = ka;  *(uint4*)&sk[nxt][lk1] = kb;
            *(uint4*)&sv[nxt][lk0] = va;  *(uint4*)&sv[nxt][lk1] = vb;
        }
        __syncthreads();
    };

    int st = 0;
    for (; st + 2 <= nst; st += 2) {
        step(0, st, true);
        step(1, st + 1, (st + 2) < nst);
    }
    if (st < nst) step(0, st, false);

    l_sum += __shfl_xor(l_sum, 16);
    l_sum += __shfl_xor(l_sum, 32);
    const float rl = __builtin_amdgcn_rcpf(l_sum);

    const size_t rowbase =
        ((size_t)((nb << 11) + q0 + wave * 16 + l15) << 10) + (hh << 6) + l4 * 4;
    #pragma unroll
    for (int ds = 0; ds < 4; ++ds) {
        uint2 o;
        o.x = pk2(acc[ds][0] * rl, acc[ds][1] * rl);
        o.y = pk2(acc[ds][2] * rl, acc[ds][3] * rl);
        *(uint2*)&y[rowbase + ds * 16] = o;
    }
}

extern "C" void kernel_launch(void* const* d_in, const int* in_sizes, int n_in,
                              void* d_out, int out_size, void* d_ws, size_t ws_size,
                              hipStream_t stream) {
    const float* x  = (const float*)d_in[0];
    const float* wq = (const float*)d_in[1];
    const float* wk = (const float*)d_in[2];
    const float* wv = (const float*)d_in[3];
    const float* wo = (const float*)d_in[4];
    float* out = (float*)d_out;

    const size_t M1 = 1u << 20;
    unsigned short* x16  = (unsigned short*)d_ws;          // 4M
    unsigned short* wq16 = x16 + 4 * M1;                   // 1M
    unsigned short* wk16 = wq16 + M1;
    unsigned short* wv16 = wk16 + M1;
    unsigned short* wot  = wv16 + M1;                      // 1M
    unsigned short* qbuf = wot + M1;                       // 4M [B,H,T,64]
    unsigned short* kbuf = qbuf + 4 * M1;                  // 4M
    unsigned short* vtb  = kbuf + 4 * M1;                  // 4M [1024][4096] sigma-perm
    unsigned short* ybuf = vtb + 4 * M1;                   // 4M [4096][1024]

    dim3 blk(256);
    prep<<<3840, blk, 0, stream>>>(x, wq, wk, wv, wo, x16, wq16, wk16, wv16, wot);
    proj<<<768, blk, 0, stream>>>(x16, wq16, wk16, wv16, qbuf, kbuf, vtb);
    attn<<<1024, blk, 0, stream>>>(qbuf, kbuf, vtb, ybuf);
    outp<<<1024, blk, 0, stream>>>(ybuf, wot, out);
}

// Round 17
// 170.083 us; speedup vs baseline: 1.0589x; 1.0047x over previous
//
#include <hip/hip_runtime.h>

// B=2, T=2048, C=1024, H=16, DQK=DV=64. Inputs fp32, output fp32, bf16 MFMA inside.

typedef short bf16x4 __attribute__((ext_vector_type(4)));
typedef short bf16x8 __attribute__((ext_vector_type(8)));
typedef float f32x4 __attribute__((ext_vector_type(4)));

#define MFMA_BF16 __builtin_amdgcn_mfma_f32_16x16x32_bf16

// log2(e)/8: Q pre-scale so softmax runs in base-2 domain (exp2 = bare v_exp_f32)
#define QSCALE 0.18033688011112042f

__device__ __forceinline__ unsigned short f2bf(float f) {
    union { float f; unsigned u; } un; un.f = f;
    unsigned r = un.u + 0x7fffu + ((un.u >> 16) & 1u);  // RNE
    return (unsigned short)(r >> 16);
}
__device__ __forceinline__ unsigned pk2(float a, float b) {
    return (unsigned)f2bf(a) | ((unsigned)f2bf(b) << 16);
}
// truncating pack of two floats into packed bf16x2
__device__ __forceinline__ unsigned pk2t(float a, float b) {
    union { float f; unsigned u; } ua, ub; ua.f = a; ub.f = b;
    return (ua.u >> 16) | (ub.u & 0xffff0000u);
}
__device__ __forceinline__ void gload16(const void* g, void* l) {
    __builtin_amdgcn_global_load_lds(
        (const __attribute__((address_space(1))) unsigned int*)g,
        (__attribute__((address_space(3))) unsigned int*)l, 16, 0, 0);
}

// ---------- fused prep: x/wq/wk/wv fp32->bf16, wo fp32->bf16 transposed ----------
__global__ __launch_bounds__(256) void prep(
    const float* __restrict__ x, const float* __restrict__ wq,
    const float* __restrict__ wk, const float* __restrict__ wv,
    const float* __restrict__ wo,
    unsigned short* __restrict__ x16, unsigned short* __restrict__ wq16,
    unsigned short* __restrict__ wk16, unsigned short* __restrict__ wv16,
    unsigned short* __restrict__ wot)
{
    const int bid = blockIdx.x;
    if (bid < 3584) {
        const float* s; unsigned short* d; int off;
        if (bid < 2048)      { s = x;  d = x16;  off = bid * 2048; }
        else if (bid < 2560) { s = wq; d = wq16; off = (bid - 2048) * 2048; }
        else if (bid < 3072) { s = wk; d = wk16; off = (bid - 2560) * 2048; }
        else                 { s = wv; d = wv16; off = (bid - 3072) * 2048; }
        int i = off + threadIdx.x * 8;
        float4 f0 = *(const float4*)&s[i], f1 = *(const float4*)&s[i + 4];
        uint4 o;
        o.x = pk2(f0.x, f0.y); o.y = pk2(f0.z, f0.w);
        o.z = pk2(f1.x, f1.y); o.w = pk2(f1.z, f1.w);
        *(uint4*)&d[i] = o;
    } else {
        // wo [K=1024][N=1024] -> wot [N][K] bf16
        __shared__ unsigned short t[64 * 72];
        const int b2 = bid - 3584;
        const int k0 = (b2 & 15) << 6, n0 = (b2 >> 4) << 6;
        const int r = threadIdx.x >> 2, cg = (threadIdx.x & 3) << 4;
        const float* src = &wo[(k0 + r) * 1024 + n0 + cg];
        #pragma unroll
        for (int j = 0; j < 16; j += 4) {
            float4 f = *(const float4*)&src[j];
            t[(cg + j + 0) * 72 + r] = f2bf(f.x);
            t[(cg + j + 1) * 72 + r] = f2bf(f.y);
            t[(cg + j + 2) * 72 + r] = f2bf(f.z);
            t[(cg + j + 3) * 72 + r] = f2bf(f.w);
        }
        __syncthreads();
        unsigned short* dst = &wot[(n0 + r) * 1024 + k0 + cg];
        unsigned short* tr = &t[r * 72 + cg];
        unsigned v[16];
        #pragma unroll
        for (int j = 0; j < 16; ++j) v[j] = tr[j];
        uint4 o0, o1;
        o0.x = v[0] | (v[1] << 16);   o0.y = v[2] | (v[3] << 16);
        o0.z = v[4] | (v[5] << 16);   o0.w = v[6] | (v[7] << 16);
        o1.x = v[8] | (v[9] << 16);   o1.y = v[10] | (v[11] << 16);
        o1.z = v[12] | (v[13] << 16); o1.w = v[14] | (v[15] << 16);
        *(uint4*)&dst[0] = o0;
        *(uint4*)&dst[8] = o1;
    }
}

// ---------- 128x128 bf16 GEMM, K=1024: BK=32 dbuf gload16, fully unrolled ----------
// R16 data-side XOR bank swizzle (validated): G-chunk = (lane&3) ^ ((r16>>1)&3);
// readers use chunk l4 ^ ((l15>>1)&3). mode 2 = vtb store with sigma permutation.
__device__ __forceinline__ void gemm_body(
    const unsigned short* __restrict__ A, const unsigned short* __restrict__ Bm,
    void* __restrict__ C, int m0, int n0, int mode, int ldc, float sc)
{
    __shared__ unsigned short sa[2][128 * 32];
    __shared__ unsigned short sb[2][128 * 32];
    const int tid = threadIdx.x, wave = tid >> 6, lane = tid & 63;
    const int l15 = lane & 15, l4 = lane >> 4;
    const int wm = (wave >> 1) << 6, wn = (wave & 1) << 6;

    const int r16 = lane >> 2;                               // 0..15
    const int gcol = (((lane & 3) ^ ((r16 >> 1) & 3)) << 3); // swizzled 16B chunk
    const int rcol = (l4 ^ ((l15 >> 1) & 3)) << 3;           // read-side chunk
    const unsigned short* Ag0 = &A[(size_t)(m0 + wave * 16 + r16) * 1024 + gcol];
    const unsigned short* Ag1 = Ag0 + (size_t)64 * 1024;
    const unsigned short* Bg0 = &Bm[(size_t)(n0 + wave * 16 + r16) * 1024 + gcol];
    const unsigned short* Bg1 = Bg0 + (size_t)64 * 1024;
    const int lb0 = (wave * 16) * 32;      // wave-uniform LDS bases (elements)
    const int lb1 = (64 + wave * 16) * 32;

    gload16(Ag0, &sa[0][lb0]);
    gload16(Ag1, &sa[0][lb1]);
    gload16(Bg0, &sb[0][lb0]);
    gload16(Bg1, &sb[0][lb1]);
    __syncthreads();

    f32x4 acc[4][4] = {};

    #pragma unroll
    for (int kk = 0; kk < 32; ++kk) {
        const int cur = kk & 1;
        if (kk < 31) {
            const int off = (kk + 1) * 32;
            const int nxt = 1 - cur;
            gload16(Ag0 + off, &sa[nxt][lb0]);
            gload16(Ag1 + off, &sa[nxt][lb1]);
            gload16(Bg0 + off, &sb[nxt][lb0]);
            gload16(Bg1 + off, &sb[nxt][lb1]);
        }
        bf16x8 af[4], bf4[4];
        #pragma unroll
        for (int i = 0; i < 4; ++i)
            af[i] = *(const bf16x8*)&sa[cur][(wm + i * 16 + l15) * 32 + rcol];
        #pragma unroll
        for (int j = 0; j < 4; ++j)
            bf4[j] = *(const bf16x8*)&sb[cur][(wn + j * 16 + l15) * 32 + rcol];
        #pragma unroll
        for (int i = 0; i < 4; ++i)
            #pragma unroll
            for (int j = 0; j < 4; ++j)
                acc[i][j] = MFMA_BF16(af[i], bf4[j], acc[i][j], 0, 0, 0);
        __syncthreads();   // next-slab loads have flown during the MFMAs above
    }

    #pragma unroll
    for (int i = 0; i < 4; ++i)
        #pragma unroll
        for (int j = 0; j < 4; ++j)
            #pragma unroll
            for (int r = 0; r < 4; ++r) {
                int row = m0 + wm + i * 16 + l4 * 4 + r;
                int col = n0 + wn + j * 16 + l15;
                float val = acc[i][j][r];
                if (mode == 0) {
                    int nb = row >> 11, t = row & 2047;
                    int hh = col >> 6, dd = col & 63;
                    ((unsigned short*)C)[(((nb << 4) + hh) * 2048 + t) * 64 + dd] =
                        f2bf(val * sc);
                } else if (mode == 1) {
                    ((float*)C)[(size_t)row * ldc + col] = val;
                } else {
                    // sigma permutation within each 32-col block (see R15)
                    int s = col & 31;
                    int cp = (col & ~31) | (((s >> 2) & 3) << 3)
                                         | (((s >> 4) & 1) << 2) | (s & 3);
                    ((unsigned short*)C)[(size_t)row * ldc + cp] = f2bf(val);
                }
            }
}

// grid 768: [0,512) QK fused | [512,768) V^T = Wv @ X^T (sigma-permuted cols)
__global__ __launch_bounds__(256) void proj(
    const unsigned short* __restrict__ x16,
    const unsigned short* __restrict__ wq16,
    const unsigned short* __restrict__ wk16,
    const unsigned short* __restrict__ wv16,
    unsigned short* __restrict__ qbuf,
    unsigned short* __restrict__ kbuf,
    unsigned short* __restrict__ vtb)
{
    const int bid = blockIdx.x;
    if (bid < 512) {
        int m0 = (bid & 31) << 7;
        int n0g = (bid >> 5) << 7;
        if (n0g < 1024)
            gemm_body(x16, wq16, qbuf, m0, n0g, 0, 0, QSCALE);
        else
            gemm_body(x16, wk16, kbuf, m0, n0g - 1024, 0, 0, 1.0f);
    } else {
        int v = bid - 512;
        gemm_body(wv16, x16, vtb, (v & 7) << 7, (v >> 3) << 7, 2, 4096, 1.0f);
    }
}

// ---------- out = Y @ Wo^T: 64x64 tiles, BK=32 dbuf gload16, swizzled ----------
__global__ __launch_bounds__(256) void outp(
    const unsigned short* __restrict__ ybuf,
    const unsigned short* __restrict__ wot,
    float* __restrict__ out)
{
    __shared__ unsigned short sa[2][64 * 32];
    __shared__ unsigned short sb[2][64 * 32];
    const int tid = threadIdx.x, wave = tid >> 6, lane = tid & 63;
    const int l15 = lane & 15, l4 = lane >> 4;
    const int bid = blockIdx.x;
    const int m0 = (bid & 63) << 6, n0 = (bid >> 6) << 6;

    const int r16 = lane >> 2;
    const int gcol = (((lane & 3) ^ ((r16 >> 1) & 3)) << 3);
    const int rcol = (l4 ^ ((l15 >> 1) & 3)) << 3;
    const unsigned short* Ag = &ybuf[(size_t)(m0 + wave * 16 + r16) * 1024 + gcol];
    const unsigned short* Bg = &wot[(size_t)(n0 + wave * 16 + r16) * 1024 + gcol];
    const int lb = (wave * 16) * 32;

    gload16(Ag, &sa[0][lb]);
    gload16(Bg, &sb[0][lb]);
    __syncthreads();

    f32x4 acc[4] = {};

    #pragma unroll
    for (int kk = 0; kk < 32; ++kk) {
        const int cur = kk & 1;
        if (kk < 31) {
            const int off = (kk + 1) * 32;
            gload16(Ag + off, &sa[1 - cur][lb]);
            gload16(Bg + off, &sb[1 - cur][lb]);
        }
        bf16x8 af = *(const bf16x8*)&sa[cur][(wave * 16 + l15) * 32 + rcol];
        #pragma unroll
        for (int j = 0; j < 4; ++j) {
            bf16x8 bf = *(const bf16x8*)&sb[cur][(j * 16 + l15) * 32 + rcol];
            acc[j] = MFMA_BF16(af, bf, acc[j], 0, 0, 0);
        }
        __syncthreads();
    }

    #pragma unroll
    for (int j = 0; j < 4; ++j)
        #pragma unroll
        for (int r = 0; r < 4; ++r) {
            int row = m0 + wave * 16 + l4 * 4 + r;
            int col = n0 + j * 16 + l15;
            out[(size_t)row * 1024 + col] = acc[j][r];
        }
}

// ---------- flash causal attention: S^T form, gload16-dbuf staging (R12 recipe) ----------
// K and V^T rows are 128B-contiguous in global, so global_load_lds stages them
// directly (no VGPR transit, no ds_write) into packed [row][64] tiles.
// Data-side XOR chunk swizzle: lane fetches global chunk (lane&7)^((lane>>3)&7),
// so LDS[r][c] = G[r][c^(r&7)]; readers use chunk (4ks+l4)^(l15&7) -> l4-group
// spreads 2-way over bank quads = free (m136). Fragment data bit-identical.
// vtb is sigma-permuted by proj, so the PV A-frag is one contiguous b128 chunk.
__global__ __launch_bounds__(256) void attn(
    const unsigned short* __restrict__ q,
    const unsigned short* __restrict__ k,
    const unsigned short* __restrict__ vt,
    unsigned short* __restrict__ y)
{
    __shared__ unsigned short sk[2][64 * 64];   // [s][d], chunk-swizzled
    __shared__ unsigned short sv[2][64 * 64];   // [d][s-perm], chunk-swizzled
    const int tid = threadIdx.x, wave = tid >> 6, lane = tid & 63;
    const int l15 = lane & 15, l4 = lane >> 4;
    const int bid = blockIdx.x;
    const int qtt = (bid < 512) ? (31 - (bid >> 5)) : ((bid - 512) >> 5);
    const int bh = bid & 31;
    const int nb = bh >> 4, hh = bh & 15;
    const int q0 = qtt << 6;
    const size_t base = (size_t)bh << 17;

    // staging coordinates: wave w call j covers rows j*32 + w*8 .. +7
    const int lrow = lane >> 3;                           // 0..7 local row
    const int gch = ((lane & 7) ^ lrow) << 3;             // swizzled chunk (elems)
    const int row0 = wave * 8 + lrow, row1 = 32 + wave * 8 + lrow;
    const unsigned short* kg0 = &k[base + (size_t)row0 * 64 + gch];   // + s0*64
    const unsigned short* kg1 = &k[base + (size_t)row1 * 64 + gch];
    const unsigned short* vg0 = &vt[(size_t)((hh << 6) + row0) * 4096 + (nb << 11) + gch];
    const unsigned short* vg1 = &vt[(size_t)((hh << 6) + row1) * 4096 + (nb << 11) + gch];
    const int lbk0 = (wave * 8) * 64, lbk1 = (32 + wave * 8) * 64;  // wave-uniform

    // Q fragments (B-operand: n=l15 -> q row, k=l4*8..+7 -> d), once per block
    bf16x8 qf[2];
    #pragma unroll
    for (int ks = 0; ks < 2; ++ks)
        qf[ks] = *(const bf16x8*)
            &q[base + (size_t)(q0 + wave * 16 + l15) * 64 + ks * 32 + l4 * 8];

    float l_sum = 0.f;
    f32x4 acc[4] = {};

    const int nst = qtt + 1;

    // read-side swizzled chunk offset for kf/vf (elements)
    const int rch0 = ((0 + l4) ^ (l15 & 7)) << 3;   // ks=0
    const int rch1 = ((4 + l4) ^ (l15 & 7)) << 3;   // ks=1

    // prologue: stage tile 0
    gload16(kg0, &sk[0][lbk0]);
    gload16(kg1, &sk[0][lbk1]);
    gload16(vg0, &sv[0][lbk0]);
    gload16(vg1, &sv[0][lbk1]);
    __syncthreads();

    // step body; LITERAL cur at each call site so all LDS bases fold to imms
    auto step = [&](const int cur, const int st, const bool more) {
        if (more) {
            const int nxt = cur ^ 1;
            const int s1e = (st + 1) << 6;              // element offset along s
            gload16(kg0 + ((size_t)s1e << 6), &sk[nxt][lbk0]);
            gload16(kg1 + ((size_t)s1e << 6), &sk[nxt][lbk1]);
            gload16(vg0 + s1e, &sv[nxt][lbk0]);
            gload16(vg1 + s1e, &sv[nxt][lbk1]);
        }

        f32x4 s_acc[4] = {};
        #pragma unroll
        for (int ns = 0; ns < 4; ++ns) {
            bf16x8 kf0 = *(const bf16x8*)&sk[cur][(ns * 16 + l15) * 64 + rch0];
            bf16x8 kf1 = *(const bf16x8*)&sk[cur][(ns * 16 + l15) * 64 + rch1];
            s_acc[ns] = MFMA_BF16(kf0, qf[0], s_acc[ns], 0, 0, 0);
            s_acc[ns] = MFMA_BF16(kf1, qf[1], s_acc[ns], 0, 0, 0);
        }

        if (st == qtt) {
            const int ql = wave * 16 + l15;
            #pragma unroll
            for (int ns = 0; ns < 4; ++ns) {
                #pragma unroll
                for (int r = 0; r < 4; ++r)
                    if (ns * 16 + l4 * 4 + r > ql) s_acc[ns][r] = -1e30f;
            }
        }

        float pe[4][4];
        #pragma unroll
        for (int ns = 0; ns < 4; ++ns) {
            #pragma unroll
            for (int r = 0; r < 4; ++r) pe[ns][r] = exp2f(s_acc[ns][r]);
            l_sum += (pe[ns][0] + pe[ns][1]) + (pe[ns][2] + pe[ns][3]);
        }

        #pragma unroll
        for (int ks = 0; ks < 2; ++ks) {
            uint4 pw;
            pw.x = pk2t(pe[2 * ks][0], pe[2 * ks][1]);
            pw.y = pk2t(pe[2 * ks][2], pe[2 * ks][3]);
            pw.z = pk2t(pe[2 * ks + 1][0], pe[2 * ks + 1][1]);
            pw.w = pk2t(pe[2 * ks + 1][2], pe[2 * ks + 1][3]);
            bf16x8 pf = *(bf16x8*)&pw;
            const int rch = ks ? rch1 : rch0;
            #pragma unroll
            for (int ds = 0; ds < 4; ++ds) {
                bf16x8 vf = *(const bf16x8*)&sv[cur][(ds * 16 + l15) * 64 + rch];
                acc[ds] = MFMA_BF16(vf, pf, acc[ds], 0, 0, 0);
            }
        }
        __syncthreads();   // next tile's gload16 deposits flew during compute
    };

    int st = 0;
    for (; st + 2 <= nst; st += 2) {
        step(0, st, true);
        step(1, st + 1, (st + 2) < nst);
    }
    if (st < nst) step(0, st, false);

    l_sum += __shfl_xor(l_sum, 16);
    l_sum += __shfl_xor(l_sum, 32);
    const float rl = __builtin_amdgcn_rcpf(l_sum);

    const size_t rowbase =
        ((size_t)((nb << 11) + q0 + wave * 16 + l15) << 10) + (hh << 6) + l4 * 4;
    #pragma unroll
    for (int ds = 0; ds < 4; ++ds) {
        uint2 o;
        o.x = pk2(acc[ds][0] * rl, acc[ds][1] * rl);
        o.y = pk2(acc[ds][2] * rl, acc[ds][3] * rl);
        *(uint2*)&y[rowbase + ds * 16] = o;
    }
}

extern "C" void kernel_launch(void* const* d_in, const int* in_sizes, int n_in,
                              void* d_out, int out_size, void* d_ws, size_t ws_size,
                              hipStream_t stream) {
    const float* x  = (const float*)d_in[0];
    const float* wq = (const float*)d_in[1];
    const float* wk = (const float*)d_in[2];
    const float* wv = (const float*)d_in[3];
    const float* wo = (const float*)d_in[4];
    float* out = (float*)d_out;

    const size_t M1 = 1u << 20;
    unsigned short* x16  = (unsigned short*)d_ws;          // 4M
    unsigned short* wq16 = x16 + 4 * M1;                   // 1M
    unsigned short* wk16 = wq16 + M1;
    unsigned short* wv16 = wk16 + M1;
    unsigned short* wot  = wv16 + M1;                      // 1M
    unsigned short* qbuf = wot + M1;                       // 4M [B,H,T,64]
    unsigned short* kbuf = qbuf + 4 * M1;                  // 4M
    unsigned short* vtb  = kbuf + 4 * M1;                  // 4M [1024][4096] sigma-perm
    unsigned short* ybuf = vtb + 4 * M1;                   // 4M [4096][1024]

    dim3 blk(256);
    prep<<<3840, blk, 0, stream>>>(x, wq, wk, wv, wo, x16, wq16, wk16, wv16, wot);
    proj<<<768, blk, 0, stream>>>(x16, wq16, wk16, wv16, qbuf, kbuf, vtb);
    attn<<<1024, blk, 0, stream>>>(qbuf, kbuf, vtb, ybuf);
    outp<<<1024, blk, 0, stream>>>(ybuf, wot, out);
}